// Round 5
// baseline (121.636 us; speedup 1.0000x reference)
//
#include <hip/hip_runtime.h>
#include <math.h>

// Fused SIFT-like pipeline:
//   Sobel(3x3, pad1) -> project onto 8 orientations -> argmax -> magnitude
//   into winning bin -> depthwise 4x4 ones conv (pad2) => out (8,8,1025,1025)
//
// v5: 2 hist cols per lane (124 out cols/wave; half the shuffles & store
// instrs per output), deferred channel expansion (tiny ring -> low VGPR),
// NO LDS staging (x direct from global; L2-resident per XCD thanks to the
// batch==XCD swizzle), float2 stores on even output rows (statically known).
//
// Block = 256 threads (4 waves, stacked vertically, fully independent).
// Lane l owns hist cols j0-2+2l, j0-1+2l and out cols j0+2l, j0+2l+1.
// Out even col = S_l + S_{l+1}; odd col = B_l + S_{l+1} + A_{l+2}
// (A,B = 4-row vertical sums of the two per-lane hist cols, S = A+B).

#define TWC 124             // out cols per tile
#define WTH 16              // out rows per wave
#define BTH 64              // out rows per block
#define NCT 9               // col tiles (9*124 = 1116 >= 1025)
#define NRT 17              // row tiles
#define PLANE 1050625       // 1025*1025

__global__ __launch_bounds__(256, 4)
void sift_fused(const float* __restrict__ x,
                const float* __restrict__ ow,
                float* __restrict__ out)
{
    const int tid  = threadIdx.x;
    const int lane = tid & 63;
    const int wv   = tid >> 6;

    // XCD-aware remap: batch == XCD (8 batches, 8 XCDs, bijective)
    const int flat = blockIdx.x + NCT * (blockIdx.y + NRT * blockIdx.z);
    const int bb = flat & 7;
    const int t  = flat >> 3;            // 0..152
    const int bx = t % NCT;
    const int by = t / NCT;
    const int j0 = bx * TWC;
    const int r0 = by * BTH;

    const int rbase = r0 + WTH * wv;     // first output row of this wave
    if (rbase > 1024) return;            // no barriers anywhere

    const float* xb = x + (size_t)bb * 1024 * 1024;

    // orientation weights (uniform -> scalar regs)
    float wcn[8], wsn[8];
    #pragma unroll
    for (int o = 0; o < 8; ++o) { wcn[o] = ow[2*o]; wsn[o] = ow[2*o+1]; }

    // x columns this lane reads: c0..c0+3 (clamped addr + zero mask)
    const int c0 = j0 - 3 + 2 * lane;
    const int cc0 = min(max(c0    , 0), 1023);
    const int cc1 = min(max(c0 + 1, 0), 1023);
    const int cc2 = min(max(c0 + 2, 0), 1023);
    const int cc3 = min(max(c0 + 3, 0), 1023);
    const float mk0 = ((unsigned)(c0    ) < 1024u) ? 1.0f : 0.0f;
    const float mk1 = ((unsigned)(c0 + 1) < 1024u) ? 1.0f : 0.0f;
    const float mk2 = ((unsigned)(c0 + 2) < 1024u) ? 1.0f : 0.0f;
    const float mk3 = ((unsigned)(c0 + 3) < 1024u) ? 1.0f : 0.0f;

    // hist column validity (cols j0-2+2l, j0-1+2l)
    const int h0 = j0 - 2 + 2 * lane;
    const float cm0 = ((unsigned)h0       < 1024u) ? 1.0f : 0.0f;
    const float cm1 = ((unsigned)(h0 + 1) < 1024u) ? 1.0f : 0.0f;

    // store predicates (out cols oc0, oc0+1)
    const int oc0 = j0 + 2 * lane;
    const bool st0 = (2 * lane     < TWC) && (oc0     <= 1024);
    const bool st1 = (2 * lane + 1 < TWC) && (oc0 + 1 <= 1024);
    const bool stpair  = st0 && st1;
    const bool st0only = st0 && !st1;

    // per-channel plane base pointers (uniform)
    float* po[8];
    #pragma unroll
    for (int o = 0; o < 8; ++o) po[o] = out + (size_t)(bb * 8 + o) * PLANE;

    int vo   = rbase * 1025 + oc0;       // element offset in a plane
    int orow = rbase;                    // out row of next FIN
    int gr   = rbase - 3;                // next x row to load

    // state: d/w row-sum quads (slot = xrow & 3), ring of raw hist rows
    float q0d0,q0d1,q0w0,q0w1, q1d0,q1d1,q1w0,q1w1;
    float q2d0,q2d1,q2w0,q2w1, q3d0,q3d1,q3w0,q3w1;
    float r0m0,r0m1, r1m0,r1m1, r2m0,r2m1, r3m0,r3m1;
    int   r0ip, r1ip, r2ip, r3ip;

// load x row gr (clamped cols, masked), build d/w row sums; gr++
#define XLOAD(BD0,BD1,BW0,BW1) { \
    float x0_,x1_,x2_,x3_; \
    if ((unsigned)gr < 1024u) { \
        const float* rp = xb + ((size_t)(unsigned)gr << 10); \
        x0_ = rp[cc0]*mk0; x1_ = rp[cc1]*mk1; \
        x2_ = rp[cc2]*mk2; x3_ = rp[cc3]*mk3; \
    } else { x0_=0.0f; x1_=0.0f; x2_=0.0f; x3_=0.0f; } \
    gr++; \
    BD0 = x2_ - x0_; \
    BD1 = x3_ - x1_; \
    BW0 = x0_ + 2.0f*x1_ + x2_; \
    BW1 = x1_ + 2.0f*x2_ + x3_; \
}

// tournament argmax: identical semantics to sequential first-max
#define TOURN8(RES, GX, GY) { \
    float pj0 = (GX)*wcn[0] + (GY)*wsn[0]; \
    float pj1 = (GX)*wcn[1] + (GY)*wsn[1]; \
    float pj2 = (GX)*wcn[2] + (GY)*wsn[2]; \
    float pj3 = (GX)*wcn[3] + (GY)*wsn[3]; \
    float pj4 = (GX)*wcn[4] + (GY)*wsn[4]; \
    float pj5 = (GX)*wcn[5] + (GY)*wsn[5]; \
    float pj6 = (GX)*wcn[6] + (GY)*wsn[6]; \
    float pj7 = (GX)*wcn[7] + (GY)*wsn[7]; \
    bool g01 = pj1 > pj0; float b01 = g01 ? pj1 : pj0; int i01 = g01 ? 1 : 0; \
    bool g23 = pj3 > pj2; float b23 = g23 ? pj3 : pj2; int i23 = g23 ? 3 : 2; \
    bool g45 = pj5 > pj4; float b45 = g45 ? pj5 : pj4; int i45 = g45 ? 5 : 4; \
    bool g67 = pj7 > pj6; float b67 = g67 ? pj7 : pj6; int i67 = g67 ? 7 : 6; \
    bool gA = b23 > b01; float bA = gA ? b23 : b01; int iA = gA ? i23 : i01; \
    bool gB = b67 > b45; float bB = gB ? b67 : b45; int iB = gB ? i67 : i45; \
    RES = (bB > bA) ? iB : iA; \
}

// one hist row: load bottom x row, Sobel both cols, magnitudes, argmaxes
#define HSTEP(TD0,TD1,TW0,TW1, MD0,MD1,MW0,MW1, BD0,BD1,BW0,BW1, RM0,RM1,RIP) { \
    XLOAD(BD0,BD1,BW0,BW1) \
    float rowm = ((unsigned)(gr - 3) < 1022u) ? 1.0f : \
                 (((unsigned)(gr - 2) < 1024u) ? 1.0f : 0.0f); \
    rowm = ((unsigned)(gr - 2) < 1024u) ? 1.0f : 0.0f; \
    float gm0 = cm0 * rowm, gm1 = cm1 * rowm; \
    float gx0 = TD0 + 2.0f*MD0 + BD0; \
    float gy0 = BW0 - TW0; \
    float gx1 = TD1 + 2.0f*MD1 + BD1; \
    float gy1 = BW1 - TW1; \
    RM0 = __builtin_amdgcn_sqrtf(gx0*gx0 + gy0*gy0) * gm0; \
    RM1 = __builtin_amdgcn_sqrtf(gx1*gx1 + gy1*gy1) * gm1; \
    int i0_, i1_; \
    TOURN8(i0_, gx0, gy0) \
    TOURN8(i1_, gx1, gy1) \
    RIP = i0_ | (i1_ << 3); \
}

// finalize one out row: expand ring to 8 channels, vertical+horizontal sums,
// store float2 (even rows) or 2 dwords (odd rows). EVENK is compile-time.
#define FIN(EVENK) { \
    bool rowok = (orow <= 1024); \
    int e00 = r0ip & 7, e01 = r0ip >> 3; \
    int e10 = r1ip & 7, e11 = r1ip >> 3; \
    int e20 = r2ip & 7, e21 = r2ip >> 3; \
    int e30 = r3ip & 7, e31 = r3ip >> 3; \
    _Pragma("unroll") \
    for (int o = 0; o < 8; ++o) { \
        float a_ = (e00 == o ? r0m0 : 0.0f); \
        a_ += (e10 == o ? r1m0 : 0.0f); \
        a_ += (e20 == o ? r2m0 : 0.0f); \
        a_ += (e30 == o ? r3m0 : 0.0f); \
        float b_ = (e01 == o ? r0m1 : 0.0f); \
        b_ += (e11 == o ? r1m1 : 0.0f); \
        b_ += (e21 == o ? r2m1 : 0.0f); \
        b_ += (e31 == o ? r3m1 : 0.0f); \
        float S_ = a_ + b_; \
        float Sd_ = __shfl_down(S_, 1); \
        float Ad_ = __shfl_down(a_, 2); \
        float E_ = S_ + Sd_; \
        float O_ = b_ + Sd_ + Ad_; \
        if (EVENK) { \
            if (rowok && stpair) { \
                float2 pv; pv.x = E_; pv.y = O_; \
                *reinterpret_cast<float2*>(po[o] + vo) = pv; \
            } else if (rowok && st0only) { \
                po[o][vo] = E_; \
            } \
        } else { \
            if (rowok && st0) po[o][vo] = E_; \
            if (rowok && st1) po[o][vo + 1] = O_; \
        } \
    } \
    vo += 1025; orow++; \
}

    // prologue: preload x rows rbase-3, rbase-2; hist rows j=0,1,2
    XLOAD(q0d0,q0d1,q0w0,q0w1)
    XLOAD(q1d0,q1d1,q1w0,q1w1)
    HSTEP(q0d0,q0d1,q0w0,q0w1, q1d0,q1d1,q1w0,q1w1, q2d0,q2d1,q2w0,q2w1,
          r0m0,r0m1,r0ip)                                             // j=0
    HSTEP(q1d0,q1d1,q1w0,q1w1, q2d0,q2d1,q2w0,q2w1, q3d0,q3d1,q3w0,q3w1,
          r1m0,r1m1,r1ip)                                             // j=1
    HSTEP(q2d0,q2d1,q2w0,q2w1, q3d0,q3d1,q3w0,q3w1, q0d0,q0d1,q0w0,q0w1,
          r2m0,r2m1,r2ip)                                             // j=2

    // steady state: j = 3..18, FIN k = j-3 = 0..15 (k parity static)
    #pragma unroll 1
    for (int it = 0; it < 4; ++it) {
        HSTEP(q3d0,q3d1,q3w0,q3w1, q0d0,q0d1,q0w0,q0w1, q1d0,q1d1,q1w0,q1w1,
              r3m0,r3m1,r3ip) FIN(1)                                  // k even
        HSTEP(q0d0,q0d1,q0w0,q0w1, q1d0,q1d1,q1w0,q1w1, q2d0,q2d1,q2w0,q2w1,
              r0m0,r0m1,r0ip) FIN(0)                                  // k odd
        HSTEP(q1d0,q1d1,q1w0,q1w1, q2d0,q2d1,q2w0,q2w1, q3d0,q3d1,q3w0,q3w1,
              r1m0,r1m1,r1ip) FIN(1)                                  // k even
        HSTEP(q2d0,q2d1,q2w0,q2w1, q3d0,q3d1,q3w0,q3w1, q0d0,q0d1,q0w0,q0w1,
              r2m0,r2m1,r2ip) FIN(0)                                  // k odd
    }

#undef FIN
#undef HSTEP
#undef TOURN8
#undef XLOAD
}

extern "C" void kernel_launch(void* const* d_in, const int* in_sizes, int n_in,
                              void* d_out, int out_size, void* d_ws, size_t ws_size,
                              hipStream_t stream)
{
    (void)in_sizes; (void)n_in; (void)d_ws; (void)ws_size; (void)out_size;
    const float* x  = (const float*)d_in[0];
    const float* ow = (const float*)d_in[2];   // orient_w (10,2): rows 0..7 = [cos, sin]
    float* out = (float*)d_out;

    dim3 grid(NCT, NRT, 8);
    sift_fused<<<grid, 256, 0, stream>>>(x, ow, out);
}

// Round 6
// 88.487 us; speedup vs baseline: 1.3746x; 1.3746x over previous
//
#include <hip/hip_runtime.h>
#include <math.h>

// Fused SIFT-like pipeline:
//   Sobel(3x3, pad1) -> project onto 8 orientations -> argmax -> magnitude
//   into winning bin -> depthwise 4x4 ones conv (pad2) => out (8,8,1025,1025)
//
// v6 = v4 (LDS staging, 1 hist col/lane, pair-sum ring, batch==XCD swizzle)
// with the horizontal 4-tap sums moved off the DS pipe: __shfl_down
// (ds_bpermute, 256/wave) replaced by DPP wave_shl:1 chains (pure VALU).
// DS-pipe busy/CU drops ~28us -> ~5us by model.
//
// Block = 256 threads (4 waves), tile 61 out cols x 64 out rows; wave owns
// 16 rows. Lane l owns hist col j0-2+l; out col c = hist cols c..c+3 via
// v += shl1(v); v += shl1(shl1(v))  (wave_shl:1 DPP, zero-fill at lane 63;
// lanes 61..63 feed only and never store).

#define TWC 61              // out cols per tile
#define WTH 16              // out rows per wave
#define WPB 4               // waves per block
#define BTH (WPB*WTH)       // 64 out rows per block
#define XC 66               // staged x cols (j0-3 .. j0+62)
#define XR (BTH+5)          // 69 staged x rows
#define PLANE 1050625       // 1025*1025
#define NCT 17              // col tiles
#define NRT 17              // row tiles

// DPP wave_shl:1 (0x130): lane i <- lane i+1, zero-fill invalid (== shfl_down 1)
__device__ __forceinline__ float wshl1(float v) {
    return __int_as_float(
        __builtin_amdgcn_update_dpp(0, __float_as_int(v), 0x130, 0xf, 0xf, true));
}

__global__ __launch_bounds__(256, 4)
void sift_fused(const float* __restrict__ x,
                const float* __restrict__ ow,
                float* __restrict__ out)
{
    __shared__ float sx[XR * XC];

    const int tid  = threadIdx.x;
    const int lane = tid & 63;
    const int wv   = tid >> 6;

    // XCD-aware remap: batch == XCD (8 batches, 8 XCDs, bijective)
    const int flat = blockIdx.x + NCT * (blockIdx.y + NRT * blockIdx.z);
    const int bb = flat & 7;
    const int t  = flat >> 3;
    const int bx = t % NCT;
    const int by = t / NCT;
    const int j0 = bx * TWC;
    const int r0 = by * BTH;

    // ---- stage x tile into LDS (zero-padded at image borders) ----
    const float* xb = x + (size_t)bb * 1024 * 1024;
    for (int p = tid; p < XR * XC; p += 256) {
        int r = p / XC, c = p - r * XC;
        int gr = r0 - 3 + r, gc = j0 - 3 + c;
        float v = 0.0f;
        if ((unsigned)gr < 1024u && (unsigned)gc < 1024u)
            v = xb[(size_t)gr * 1024 + gc];
        sx[p] = v;
    }
    __syncthreads();

    const int rbase = r0 + WTH * wv;           // first output row of this wave
    if (rbase > 1024) return;                  // no barriers after this point

    // orientation weights (uniform loads)
    float wcn[8], wsn[8];
    #pragma unroll
    for (int o = 0; o < 8; ++o) { wcn[o] = ow[2*o]; wsn[o] = ow[2*o+1]; }

    const int gcol = j0 - 2 + lane;            // hist column this lane owns
    const bool colok = (unsigned)gcol < 1024u;
    const int gj = j0 + lane;                  // output column this lane stores
    const bool canstore = (lane < TWC) && (gj <= 1024);

    // 8 uniform per-channel plane base pointers
    float* po[8];
    #pragma unroll
    for (int o = 0; o < 8; ++o) po[o] = out + (size_t)(bb * 8 + o) * PLANE;

    const float* px = sx + (WTH * wv) * XC + lane;  // x row cursor (3 cols/lane)
    int hrow = rbase - 2;                      // global hist row of current step
    int orow = rbase;                          // global out row of next FIN
    int vo   = rbase * 1025 + gj;              // element offset within a plane

    // register state: d/w row-sum rings (slot = xrow & 3), contrib ping-pong,
    // pair-sum ring (slot = histrow & 3)
    float dd0, dd1, dd2, dd3, ww0, ww1, ww2, ww3;
    float cA[8], cB[8], PP0[8], PP1[8], PP2[8], PP3[8];

#define XROWLOAD(DD, WW) { \
    float n0 = px[0], n1 = px[1], n2 = px[2]; px += XC; \
    DD = n2 - n0; \
    WW = n0 + 2.0f*n1 + n2; \
}

// One hist row: load x row j+2 -> (DB,WB); Sobel from rings; magnitude;
// tournament argmax (== sequential first-max); one-hot contrib CC;
// pair sum PC = CP + CC; optional FIN of out row j-3.
#define HSTEP(DT, DM, DB, WT, WB, CP, CC, PR, PC, DOP, DOFIN) { \
    XROWLOAD(DB, WB) \
    float gx = DT + 2.0f*DM + DB; \
    float gy = WB - WT; \
    float msq = gx*gx + gy*gy; \
    float m = (colok && (unsigned)hrow < 1024u) \
                ? __builtin_amdgcn_sqrtf(msq) : 0.0f; \
    hrow++; \
    float pj0 = gx*wcn[0] + gy*wsn[0]; \
    float pj1 = gx*wcn[1] + gy*wsn[1]; \
    float pj2 = gx*wcn[2] + gy*wsn[2]; \
    float pj3 = gx*wcn[3] + gy*wsn[3]; \
    float pj4 = gx*wcn[4] + gy*wsn[4]; \
    float pj5 = gx*wcn[5] + gy*wsn[5]; \
    float pj6 = gx*wcn[6] + gy*wsn[6]; \
    float pj7 = gx*wcn[7] + gy*wsn[7]; \
    bool g01 = pj1 > pj0; float b01 = g01 ? pj1 : pj0; int i01 = g01 ? 1 : 0; \
    bool g23 = pj3 > pj2; float b23 = g23 ? pj3 : pj2; int i23 = g23 ? 3 : 2; \
    bool g45 = pj5 > pj4; float b45 = g45 ? pj5 : pj4; int i45 = g45 ? 5 : 4; \
    bool g67 = pj7 > pj6; float b67 = g67 ? pj7 : pj6; int i67 = g67 ? 7 : 6; \
    bool gA = b23 > b01; float bA = gA ? b23 : b01; int iA = gA ? i23 : i01; \
    bool gB = b67 > b45; float bB = gB ? b67 : b45; int iB = gB ? i67 : i45; \
    int idx = (bB > bA) ? iB : iA; \
    _Pragma("unroll") \
    for (int o = 0; o < 8; ++o) CC[o] = (idx == o) ? m : 0.0f; \
    if (DOP) { \
        _Pragma("unroll") \
        for (int o = 0; o < 8; ++o) PC[o] = CP[o] + CC[o]; \
    } \
    if (DOFIN) { \
        bool ok = canstore && (orow <= 1024); \
        _Pragma("unroll") \
        for (int o = 0; o < 8; ++o) { \
            float v = PR[o] + PC[o]; \
            v += wshl1(v);                 /* + lane l+1            */ \
            v += wshl1(wshl1(v));          /* + lanes l+2, l+3      */ \
            if (ok) po[o][vo] = v; \
        } \
        vo += 1025; orow++; \
    } \
}

    // prologue: x rows 0,1 then hist rows j=0..2 (no FIN yet)
    XROWLOAD(dd0, ww0)
    XROWLOAD(dd1, ww1)
    HSTEP(dd0, dd1, dd2, ww0, ww2, cA, cB, PP0, PP0, 0, 0)   // j=0 (P_0 unused)
    HSTEP(dd1, dd2, dd3, ww1, ww3, cB, cA, PP0, PP1, 1, 0)   // j=1
    HSTEP(dd2, dd3, dd0, ww2, ww0, cA, cB, PP0, PP2, 1, 0)   // j=2

    // steady state: j = 3..18, FIN t = j-3 = 0..15
    #pragma unroll 1
    for (int it = 0; it < 4; ++it) {
        HSTEP(dd3, dd0, dd1, ww3, ww1, cB, cA, PP1, PP3, 1, 1)   // j%4==3
        HSTEP(dd0, dd1, dd2, ww0, ww2, cA, cB, PP2, PP0, 1, 1)   // j%4==0
        HSTEP(dd1, dd2, dd3, ww1, ww3, cB, cA, PP3, PP1, 1, 1)   // j%4==1
        HSTEP(dd2, dd3, dd0, ww2, ww0, cA, cB, PP0, PP2, 1, 1)   // j%4==2
    }

#undef HSTEP
#undef XROWLOAD
}

extern "C" void kernel_launch(void* const* d_in, const int* in_sizes, int n_in,
                              void* d_out, int out_size, void* d_ws, size_t ws_size,
                              hipStream_t stream)
{
    (void)in_sizes; (void)n_in; (void)d_ws; (void)ws_size; (void)out_size;
    const float* x  = (const float*)d_in[0];
    const float* ow = (const float*)d_in[2];   // orient_w (10,2): rows 0..7 = [cos, sin]
    float* out = (float*)d_out;

    dim3 grid(NCT, NRT, 8);
    sift_fused<<<grid, 256, 0, stream>>>(x, ow, out);
}